// Round 2
// baseline (269.046 us; speedup 1.0000x reference)
//
#include <hip/hip_runtime.h>
#include <hip/hip_bf16.h>
#include <cstdint>
#include <cstddef>

typedef __attribute__((ext_vector_type(8))) short short8;
typedef __attribute__((ext_vector_type(4))) float f32x4;
typedef unsigned short u16;
typedef unsigned int u32;

#define NB 2
#define NS 2048
#define ND 1024
#define NH 16
#define NDK 64

// float -> bf16 round-to-nearest-even
__device__ __forceinline__ u16 f2bf(float f){
  u32 u = __builtin_bit_cast(u32, f);
  u += 0x7fffu + ((u >> 16) & 1u);
  return (u16)(u >> 16);
}

__device__ __forceinline__ short8 mk8(ushort4 lo, ushort4 hi){
  short8 r;
  r[0]=(short)lo.x; r[1]=(short)lo.y; r[2]=(short)lo.z; r[3]=(short)lo.w;
  r[4]=(short)hi.x; r[5]=(short)hi.y; r[6]=(short)hi.z; r[7]=(short)hi.w;
  return r;
}

// ---------------- transpose weights: W (K x N) f32 -> Wt (N x K) bf16 ----------------
__global__ __launch_bounds__(256) void transpose_w_kernel(
    const float* __restrict__ Wq, const float* __restrict__ Wk,
    const float* __restrict__ Wv, const float* __restrict__ Wo,
    u16* __restrict__ Wt)
{
  const int z = blockIdx.z;
  const float* W = (z==0)?Wq:(z==1)?Wk:(z==2)?Wv:Wo;
  u16* dst = Wt + (size_t)z*ND*ND;
  __shared__ float t[32][33];
  const int tx = threadIdx.x, ty = threadIdx.y;   // 32 x 8
  const int n0 = blockIdx.x*32, k0 = blockIdx.y*32;
#pragma unroll
  for (int i=0;i<4;i++) t[ty+i*8][tx] = W[(size_t)(k0+ty+i*8)*ND + n0+tx];
  __syncthreads();
#pragma unroll
  for (int i=0;i<4;i++) dst[(size_t)(n0+ty+i*8)*ND + k0+tx] = f2bf(t[tx][ty+i*8]);
}

// ---------------- GEMM: C(128x128 tiles) = A(M x 1024) * W(1024 x N) + bias ----------------
// MODE 0: A = x (f32), z in {0,1,2} -> Q (scaled by 0.125*log2e), K, Vt(B,H,DK,S)  [bf16 out]
// MODE 1: A = O (bf16) -> d_out = O @ Wo + bo  [f32 out]
template<int MODE>
__global__ __launch_bounds__(256) void gemm_kernel(
    const float* __restrict__ Af32, const u16* __restrict__ Abf,
    const u16* __restrict__ Wtz,
    const float* __restrict__ bias0, const float* __restrict__ bias1, const float* __restrict__ bias2,
    u16* __restrict__ Qout, u16* __restrict__ Kout, u16* __restrict__ Vtout,
    float* __restrict__ Fout)
{
  const int tid  = threadIdx.x;
  const int lane = tid & 63;
  const int wv   = tid >> 6;
  const int a = lane & 15, g = lane >> 4;
  const int wm = wv >> 1, wn = wv & 1;
  const int m0 = blockIdx.y * 128, n0 = blockIdx.x * 128;
  const int z  = (MODE==0) ? (int)blockIdx.z : 0;
  const u16* Wz = Wtz + (size_t)z * (ND*ND);

  __shared__ u16 Al[128][40];   // stride 80B: 16B-aligned rows, conflict-min reads
  __shared__ u16 Bl[128][40];

  f32x4 acc[4][4] = {};

  const int row = tid >> 1;
  const int c0  = (tid & 1) * 16;

#pragma unroll 1
  for (int k0 = 0; k0 < ND; k0 += 32) {
    __syncthreads();
    if constexpr (MODE==0) {
      const float* src = Af32 + (size_t)(m0+row)*ND + k0 + c0;
      float4 v0 = *(const float4*)(src+0);
      float4 v1 = *(const float4*)(src+4);
      float4 v2 = *(const float4*)(src+8);
      float4 v3 = *(const float4*)(src+12);
      ushort4 t0 = make_ushort4(f2bf(v0.x), f2bf(v0.y), f2bf(v0.z), f2bf(v0.w));
      ushort4 t1 = make_ushort4(f2bf(v1.x), f2bf(v1.y), f2bf(v1.z), f2bf(v1.w));
      ushort4 t2 = make_ushort4(f2bf(v2.x), f2bf(v2.y), f2bf(v2.z), f2bf(v2.w));
      ushort4 t3 = make_ushort4(f2bf(v3.x), f2bf(v3.y), f2bf(v3.z), f2bf(v3.w));
      *(ushort4*)&Al[row][c0+0]  = t0;
      *(ushort4*)&Al[row][c0+4]  = t1;
      *(ushort4*)&Al[row][c0+8]  = t2;
      *(ushort4*)&Al[row][c0+12] = t3;
    } else {
      const u16* src = Abf + (size_t)(m0+row)*ND + k0 + c0;
      uint4 u0 = *(const uint4*)(src);
      uint4 u1 = *(const uint4*)(src+8);
      *(uint4*)&Al[row][c0]   = u0;
      *(uint4*)&Al[row][c0+8] = u1;
    }
    {
      const u16* srcw = Wz + (size_t)(n0+row)*ND + k0 + c0;
      uint4 w0 = *(const uint4*)(srcw);
      uint4 w1 = *(const uint4*)(srcw+8);
      *(uint4*)&Bl[row][c0]   = w0;
      *(uint4*)&Bl[row][c0+8] = w1;
    }
    __syncthreads();

    short8 af[4], bfr[4];
#pragma unroll
    for (int mi=0;mi<4;++mi){
      const int rr = wm*64 + mi*16 + a;
      ushort4 lo = *(const ushort4*)&Al[rr][4*g];
      ushort4 hi = *(const ushort4*)&Al[rr][16+4*g];
      af[mi] = mk8(lo,hi);
    }
#pragma unroll
    for (int ni=0;ni<4;++ni){
      const int rr = wn*64 + ni*16 + a;
      ushort4 lo = *(const ushort4*)&Bl[rr][4*g];
      ushort4 hi = *(const ushort4*)&Bl[rr][16+4*g];
      bfr[ni] = mk8(lo,hi);
    }
#pragma unroll
    for (int mi=0;mi<4;++mi)
#pragma unroll
      for (int ni=0;ni<4;++ni)
        acc[mi][ni] = __builtin_amdgcn_mfma_f32_16x16x32_bf16(af[mi], bfr[ni], acc[mi][ni], 0,0,0);
  }

  // epilogue: lane holds D[4g+r][a] per 16x16 tile (HW-verified C/D layout)
#pragma unroll
  for (int mi=0;mi<4;++mi){
#pragma unroll
    for (int ni=0;ni<4;++ni){
      const int n  = n0 + wn*64 + ni*16 + a;
      const int mb = m0 + wm*64 + mi*16 + 4*g;
      if constexpr (MODE==0){
        const float* bp = (z==0)? bias0 : (z==1)? bias1 : bias2;
        const float bias = bp[n];
        const int h = n >> 6, dk = n & 63;
        const int b = mb >> 11, s = mb & 2047;
        if (z==2){
          ushort4 st;
          st.x = f2bf(acc[mi][ni][0]+bias);
          st.y = f2bf(acc[mi][ni][1]+bias);
          st.z = f2bf(acc[mi][ni][2]+bias);
          st.w = f2bf(acc[mi][ni][3]+bias);
          *(ushort4*)&Vtout[(((size_t)b*NH + h)*NDK + dk)*NS + s] = st;  // V transposed
        } else {
          u16* dst = (z==0)? Qout : Kout;
          const float sc = (z==0)? 0.1803368801111601f : 1.0f;  // 0.125*log2(e) folded into Q
#pragma unroll
          for (int r=0;r<4;++r)
            dst[(((size_t)b*NH + h)*NS + (s+r))*NDK + dk] = f2bf((acc[mi][ni][r]+bias)*sc);
        }
      } else {
        const float bias = bias0[n];
#pragma unroll
        for (int r=0;r<4;++r)
          Fout[(size_t)(mb+r)*ND + n] = acc[mi][ni][r] + bias;
      }
    }
  }
}

// ---------------- flash attention (causal), swapped-QK^T, exp2 domain ----------------
// 4 waves x 32 q-rows = 128 q/block; KV tiles of 64, double-buffered XOR-swizzled LDS.
// grid: (S/128, B*H), heavy blocks first. Q pre-scaled by 0.125*log2e.

// XOR swizzle in u16 units for [64][64] bf16 tiles (128B rows): byte ^= (row&7)<<4
#define SW(r_, c_) (((r_)<<6) + ((c_) ^ ((((r_)&7))<<3)))

__global__ __launch_bounds__(256) void attn_kernel(
    const u16* __restrict__ Qg, const u16* __restrict__ Kg,
    const u16* __restrict__ Vtg, u16* __restrict__ Og)
{
  const int tid  = threadIdx.x;
  const int lane = tid & 63, wv = tid >> 6;
  const int a = lane & 15, g = lane >> 4;
  const int qbx = (int)gridDim.x - 1 - (int)blockIdx.x;   // heavy blocks dispatch first
  const int bh  = blockIdx.y;
  const int qB  = qbx * 128;
  const int q0w = qB + wv * 32;
  const int nt  = 2*qbx + 2;     // KV tiles of 64 covering [0, qB+128)

  __shared__ u16 Ks[2][64*64];
  __shared__ u16 Vs[2][64*64];

  // hoist Q fragments (B-operand): qf[qi][dkh], q = q0w + qi*16 + a
  short8 qf[2][2];
#pragma unroll
  for (int qi=0; qi<2; ++qi){
    const u16* qptr = Qg + ((size_t)bh*NS + q0w + qi*16 + a)*NDK;
#pragma unroll
    for (int dkh=0; dkh<2; ++dkh){
      ushort4 lo = *(const ushort4*)(qptr + 32*dkh + 4*g);
      ushort4 hi = *(const ushort4*)(qptr + 32*dkh + 16 + 4*g);
      qf[qi][dkh] = mk8(lo,hi);
    }
  }

  float mrun[2] = {-1e30f, -1e30f};
  float ls[2]   = {0.f, 0.f};
  f32x4 accO[4][2] = {};

  // cooperative staging geometry: 256 threads x 2 x 16B chunks per tile
  const int srow = tid >> 3;          // 0..31
  const int scol = (tid & 7) * 8;     // u16 col
  const size_t kbase = (size_t)bh * NS;
  const size_t vbase = (size_t)bh * NDK;

  // prologue: stage tile 0 into buffer 0
#pragma unroll
  for (int i=0;i<2;++i){
    const int r = srow + i*32;
    uint4 kd = *(const uint4*)(Kg + (kbase + r)*NDK + scol);
    *(uint4*)&Ks[0][SW(r, scol)] = kd;
    uint4 vd = *(const uint4*)(Vtg + (vbase + r)*NS + scol);
    *(uint4*)&Vs[0][SW(r, scol)] = vd;
  }
  __syncthreads();

  int cur = 0;
#pragma unroll 1
  for (int t=0; t<nt; ++t){
    const int kv0 = t * 64;
    const bool have_next = (t+1 < nt);
    uint4 knx[2], vnx[2];
    if (have_next){                      // T14: issue global loads early
      const int kv1 = kv0 + 64;
#pragma unroll
      for (int i=0;i<2;++i){
        const int r = srow + i*32;
        knx[i] = *(const uint4*)(Kg + (kbase + kv1 + r)*NDK + scol);
        vnx[i] = *(const uint4*)(Vtg + (vbase + r)*NS + kv1 + scol);
      }
    }

    if (kv0 <= q0w + 31){                // wave-uniform participation
      const u16* Kb = &Ks[cur][0];
      const u16* Vb = &Vs[cur][0];
      // S^T = K * Q^T : sc[qi][kvf], lane holds S^T[kv0+kvf*16+4g+r][q0w+qi*16+a]
      f32x4 sc[2][4] = {};
#pragma unroll
      for (int kvf=0; kvf<4; ++kvf){
        short8 kf[2];
#pragma unroll
        for (int dkh=0; dkh<2; ++dkh){
          ushort4 lo = *(const ushort4*)&Kb[SW(kvf*16 + a, 32*dkh + 4*g)];
          ushort4 hi = *(const ushort4*)&Kb[SW(kvf*16 + a, 32*dkh + 16 + 4*g)];
          kf[dkh] = mk8(lo,hi);
        }
#pragma unroll
        for (int qi=0; qi<2; ++qi){
          sc[qi][kvf] = __builtin_amdgcn_mfma_f32_16x16x32_bf16(kf[0], qf[qi][0], sc[qi][kvf], 0,0,0);
          sc[qi][kvf] = __builtin_amdgcn_mfma_f32_16x16x32_bf16(kf[1], qf[qi][1], sc[qi][kvf], 0,0,0);
        }
      }

      const bool diag = (kv0 + 63 > q0w);
      short8 pf[2][2];
#pragma unroll
      for (int qi=0; qi<2; ++qi){
        const int q = q0w + qi*16 + a;
        float tmax = -1e30f;
        if (diag){
#pragma unroll
          for (int kvf=0; kvf<4; ++kvf)
#pragma unroll
            for (int r=0; r<4; ++r){
              const int kv = kv0 + kvf*16 + 4*g + r;
              if (kv > q) sc[qi][kvf][r] = -1e30f;
              tmax = fmaxf(tmax, sc[qi][kvf][r]);
            }
        } else {
#pragma unroll
          for (int kvf=0; kvf<4; ++kvf)
#pragma unroll
            for (int r=0; r<4; ++r)
              tmax = fmaxf(tmax, sc[qi][kvf][r]);
        }
        tmax = fmaxf(tmax, __shfl_xor(tmax, 16));
        tmax = fmaxf(tmax, __shfl_xor(tmax, 32));
        const float mnew = fmaxf(mrun[qi], tmax);
        const float fsc  = exp2f(mrun[qi] - mnew);
        mrun[qi] = mnew;
        float rsum = 0.f;
#pragma unroll
        for (int kvf=0; kvf<4; ++kvf)
#pragma unroll
          for (int r=0; r<4; ++r){
            const float p = exp2f(sc[qi][kvf][r] - mnew);
            rsum += p;
            pf[qi][kvf>>1][(kvf&1)*4 + r] = (short)f2bf(p);
          }
        rsum += __shfl_xor(rsum, 16);
        rsum += __shfl_xor(rsum, 32);
        ls[qi] = ls[qi]*fsc + rsum;
#pragma unroll
        for (int dkg=0; dkg<4; ++dkg) accO[dkg][qi] *= fsc;
      }

      // PV: out^T(dk x q) += V^T * P^T (P in-register as B-operand)
#pragma unroll
      for (int dkg=0; dkg<4; ++dkg){
#pragma unroll
        for (int kvh=0; kvh<2; ++kvh){
          ushort4 lo = *(const ushort4*)&Vb[SW(dkg*16 + a, kvh*32 + 4*g)];
          ushort4 hi = *(const ushort4*)&Vb[SW(dkg*16 + a, kvh*32 + 16 + 4*g)];
          const short8 vf = mk8(lo,hi);
#pragma unroll
          for (int qi=0; qi<2; ++qi)
            accO[dkg][qi] = __builtin_amdgcn_mfma_f32_16x16x32_bf16(vf, pf[qi][kvh], accO[dkg][qi], 0,0,0);
        }
      }
    }

    if (have_next){                      // T14: LDS write after compute
#pragma unroll
      for (int i=0;i<2;++i){
        const int r = srow + i*32;
        *(uint4*)&Ks[cur^1][SW(r, scol)] = knx[i];
        *(uint4*)&Vs[cur^1][SW(r, scol)] = vnx[i];
      }
    }
    __syncthreads();
    cur ^= 1;
  }

  // epilogue: lane's acc belongs to q = q0w + qi*16 + a; dk = dkg*16 + 4g + r
  const int b = bh >> 4, h = bh & 15;
#pragma unroll
  for (int qi=0; qi<2; ++qi){
    const float inv = 1.0f / ls[qi];
    u16* op = Og + ((size_t)b*NS + (q0w + qi*16 + a))*ND + h*NDK;
#pragma unroll
    for (int dkg=0; dkg<4; ++dkg){
      ushort4 st;
      st.x = f2bf(accO[dkg][qi][0]*inv);
      st.y = f2bf(accO[dkg][qi][1]*inv);
      st.z = f2bf(accO[dkg][qi][2]*inv);
      st.w = f2bf(accO[dkg][qi][3]*inv);
      *(ushort4*)(op + dkg*16 + 4*g) = st;
    }
  }
}

extern "C" void kernel_launch(void* const* d_in, const int* in_sizes, int n_in,
                              void* d_out, int out_size, void* d_ws, size_t ws_size,
                              hipStream_t stream) {
  (void)in_sizes; (void)n_in; (void)out_size; (void)ws_size;
  const float* x  = (const float*)d_in[0];
  // d_in[1] = mask: causal triu(k=1), hardcoded in attn kernel
  const float* Wq = (const float*)d_in[2];
  const float* bq = (const float*)d_in[3];
  const float* Wk = (const float*)d_in[4];
  const float* bk = (const float*)d_in[5];
  const float* Wv = (const float*)d_in[6];
  const float* bv = (const float*)d_in[7];
  const float* Wo = (const float*)d_in[8];
  const float* bo = (const float*)d_in[9];
  float* out = (float*)d_out;

  // workspace layout (bf16 elems): Wt[4MB elems] | Q | K | Vt | O  (40 MB total)
  u16* Wt  = (u16*)d_ws;
  u16* Qb  = Wt  + (size_t)4*1024*1024;
  u16* Kb  = Qb  + (size_t)4194304;
  u16* Vtb = Kb  + (size_t)4194304;
  u16* Ob  = Vtb + (size_t)4194304;

  transpose_w_kernel<<<dim3(32,32,4), dim3(32,8,1), 0, stream>>>(Wq, Wk, Wv, Wo, Wt);
  gemm_kernel<0><<<dim3(8,32,3), dim3(256), 0, stream>>>(
      x, (const u16*)nullptr, Wt, bq, bk, bv, Qb, Kb, Vtb, (float*)nullptr);
  attn_kernel<<<dim3(16,32), dim3(256), 0, stream>>>(Qb, Kb, Vtb, Ob);
  gemm_kernel<1><<<dim3(8,32,1), dim3(256), 0, stream>>>(
      (const float*)nullptr, Ob, Wt + (size_t)3*1024*1024, bo, nullptr, nullptr,
      (u16*)nullptr, (u16*)nullptr, (u16*)nullptr, out);
}

// Round 3
// 162.094 us; speedup vs baseline: 1.6598x; 1.6598x over previous
//
#include <hip/hip_runtime.h>
#include <hip/hip_bf16.h>
#include <cstdint>
#include <cstddef>

typedef __attribute__((ext_vector_type(8))) short short8;
typedef __attribute__((ext_vector_type(4))) float f32x4;
typedef unsigned short u16;
typedef unsigned int u32;

#define NB 2
#define NS 2048
#define ND 1024
#define NH 16
#define NDK 64

// float -> bf16 round-to-nearest-even
__device__ __forceinline__ u16 f2bf(float f){
  u32 u = __builtin_bit_cast(u32, f);
  u += 0x7fffu + ((u >> 16) & 1u);
  return (u16)(u >> 16);
}

__device__ __forceinline__ short8 mk8(ushort4 lo, ushort4 hi){
  short8 r;
  r[0]=(short)lo.x; r[1]=(short)lo.y; r[2]=(short)lo.z; r[3]=(short)lo.w;
  r[4]=(short)hi.x; r[5]=(short)hi.y; r[6]=(short)hi.z; r[7]=(short)hi.w;
  return r;
}

// async global->LDS, 16B per lane. LDS dest must be wave-uniform base (lane i lands
// at base + 16*i); global src is per-lane (pre-swizzle there for swizzled LDS).
__device__ __forceinline__ void stage16(const u16* g, u16* l, int lane){
#if defined(__has_builtin) && __has_builtin(__builtin_amdgcn_global_load_lds)
  __builtin_amdgcn_global_load_lds(
      (const __attribute__((address_space(1))) u32*)(const void*)g,
      (__attribute__((address_space(3))) u32*)(void*)l, 16, 0, 0);
#else
  ((uint4*)l)[lane] = *(const uint4*)g;
#endif
}

// ---------------- cast x (f32) -> xb (bf16) ----------------
__global__ __launch_bounds__(256) void cast_x_kernel(const float* __restrict__ x, u16* __restrict__ xb){
  const int i = ((int)blockIdx.x*256 + (int)threadIdx.x)*8;
  float4 v0 = *(const float4*)(x+i);
  float4 v1 = *(const float4*)(x+i+4);
  ushort4 lo = make_ushort4(f2bf(v0.x),f2bf(v0.y),f2bf(v0.z),f2bf(v0.w));
  ushort4 hi = make_ushort4(f2bf(v1.x),f2bf(v1.y),f2bf(v1.z),f2bf(v1.w));
  *(short8*)(xb+i) = mk8(lo,hi);
}

// ---------------- transpose weights: W (K x N) f32 -> Wt (N x K) bf16 ----------------
__global__ __launch_bounds__(256) void transpose_w_kernel(
    const float* __restrict__ Wq, const float* __restrict__ Wk,
    const float* __restrict__ Wv, const float* __restrict__ Wo,
    u16* __restrict__ Wt)
{
  const int z = blockIdx.z;
  const float* W = (z==0)?Wq:(z==1)?Wk:(z==2)?Wv:Wo;
  u16* dst = Wt + (size_t)z*ND*ND;
  __shared__ float t[32][33];
  const int tx = threadIdx.x, ty = threadIdx.y;   // 32 x 8
  const int n0 = blockIdx.x*32, k0 = blockIdx.y*32;
#pragma unroll
  for (int i=0;i<4;i++) t[ty+i*8][tx] = W[(size_t)(k0+ty+i*8)*ND + n0+tx];
  __syncthreads();
#pragma unroll
  for (int i=0;i<4;i++) dst[(size_t)(n0+ty+i*8)*ND + k0+tx] = f2bf(t[tx][ty+i*8]);
}

// ---------------- GEMM: C(128x128) = A(M x 1024)bf16 * W(1024 x N) + bias ----------------
// BK=64, global_load_lds staging with XOR-swizzled source, linear LDS, swizzled reads.
// MODE 0: z in {0,1,2} -> Q (scaled by 0.125*log2e), K, Vt(B,H,DK,S)  [bf16 out]
// MODE 1: -> d_out = A @ Wo + bo  [f32 out]
template<int MODE>
__global__ __launch_bounds__(256,3) void gemm_kernel(
    const u16* __restrict__ Abf, const u16* __restrict__ Wtz,
    const float* __restrict__ bias0, const float* __restrict__ bias1, const float* __restrict__ bias2,
    u16* __restrict__ Qout, u16* __restrict__ Kout, u16* __restrict__ Vtout,
    float* __restrict__ Fout)
{
  const int tid  = threadIdx.x;
  const int lane = tid & 63;
  const int wv   = tid >> 6;
  const int a = lane & 15, g = lane >> 4;
  const int wm = wv >> 1, wn = wv & 1;
  const int m0 = blockIdx.y * 128, n0 = blockIdx.x * 128;
  const int z  = (MODE==0) ? (int)blockIdx.z : 0;
  const u16* Wz = Wtz + (size_t)z * (ND*ND);

  __shared__ u16 Al[128*64];
  __shared__ u16 Bl[128*64];

  f32x4 acc[4][4] = {};

  const int grow = lane >> 3;         // row within 8-row staging group
  const int gcol = (lane & 7) * 8;    // u16 col

#pragma unroll 1
  for (int k0 = 0; k0 < ND; k0 += 64) {
    __syncthreads();
#pragma unroll
    for (int i=0;i<4;++i){
      const int r = 32*wv + 8*i + grow;
      const int cs = gcol ^ ((r&7)<<3);
      stage16(Abf + (size_t)(m0+r)*ND + k0 + cs, &Al[(32*wv+8*i)*64], lane);
      stage16(Wz  + (size_t)(n0+r)*ND + k0 + cs, &Bl[(32*wv+8*i)*64], lane);
    }
    __syncthreads();

#pragma unroll
    for (int kk=0; kk<64; kk+=32){
      short8 af[4], bfr[4];
#pragma unroll
      for (int mi=0;mi<4;++mi){
        const int rr = wm*64 + mi*16 + a;
        const int rsw = (rr&7)<<3;
        const u16* rp = &Al[rr*64];
        af[mi] = mk8(*(const ushort4*)(rp + ((kk+4*g)^rsw)),
                     *(const ushort4*)(rp + ((kk+16+4*g)^rsw)));
      }
#pragma unroll
      for (int ni=0;ni<4;++ni){
        const int rr = wn*64 + ni*16 + a;
        const int rsw = (rr&7)<<3;
        const u16* rp = &Bl[rr*64];
        bfr[ni] = mk8(*(const ushort4*)(rp + ((kk+4*g)^rsw)),
                      *(const ushort4*)(rp + ((kk+16+4*g)^rsw)));
      }
      __builtin_amdgcn_s_setprio(1);
#pragma unroll
      for (int mi=0;mi<4;++mi)
#pragma unroll
        for (int ni=0;ni<4;++ni)
          acc[mi][ni] = __builtin_amdgcn_mfma_f32_16x16x32_bf16(af[mi], bfr[ni], acc[mi][ni], 0,0,0);
      __builtin_amdgcn_s_setprio(0);
    }
  }

  // epilogue: lane holds D[4g+r][a] per 16x16 tile (HW-verified C/D layout)
#pragma unroll
  for (int mi=0;mi<4;++mi){
#pragma unroll
    for (int ni=0;ni<4;++ni){
      const int n  = n0 + wn*64 + ni*16 + a;
      const int mb = m0 + wm*64 + mi*16 + 4*g;
      if constexpr (MODE==0){
        const float* bp = (z==0)? bias0 : (z==1)? bias1 : bias2;
        const float bias = bp[n];
        const int h = n >> 6, dk = n & 63;
        const int b = mb >> 11, s = mb & 2047;
        if (z==2){
          ushort4 st;
          st.x = f2bf(acc[mi][ni][0]+bias);
          st.y = f2bf(acc[mi][ni][1]+bias);
          st.z = f2bf(acc[mi][ni][2]+bias);
          st.w = f2bf(acc[mi][ni][3]+bias);
          *(ushort4*)&Vtout[(((size_t)b*NH + h)*NDK + dk)*NS + s] = st;  // V transposed
        } else {
          u16* dst = (z==0)? Qout : Kout;
          const float sc = (z==0)? 0.1803368801111601f : 1.0f;  // 0.125*log2(e) folded into Q
#pragma unroll
          for (int r=0;r<4;++r)
            dst[(((size_t)b*NH + h)*NS + (s+r))*NDK + dk] = f2bf((acc[mi][ni][r]+bias)*sc);
        }
      } else {
        const float bias = bias0[n];
#pragma unroll
        for (int r=0;r<4;++r)
          Fout[(size_t)(mb+r)*ND + n] = acc[mi][ni][r] + bias;
      }
    }
  }
}

// ---------------- flash attention (causal), swapped-QK^T, exp2 domain ----------------
// grid (bh=32, qt=32); 4 waves x 16 q-rows = 64 q/block; KVB=64, dbuf swizzled LDS.
// qt->qb permutation makes each CU's stride-256 co-resident set sum to constant work.
#define SW(r_, c_) (((r_)<<6) + ((c_) ^ ((((r_)&7))<<3)))

__global__ __launch_bounds__(256,4) void attn_kernel(
    const u16* __restrict__ Qg, const u16* __restrict__ Kg,
    const u16* __restrict__ Vtg, u16* __restrict__ Og)
{
  const int tid  = threadIdx.x;
  const int lane = tid & 63, wv = tid >> 6;
  const int a = lane & 15, g = lane >> 4;
  const int bh = blockIdx.x;
  const int qt = blockIdx.y;
  const int s_ = qt >> 3, g_ = qt & 7;
  const int qb = s_*8 + ((s_ & 1) ? g_ : (7 - g_));   // balanced bijection
  const int q0w = qb*64 + wv*16;
  const int q   = q0w + a;
  const int nt  = qb + 1;           // KV tiles of 64

  __shared__ u16 Ks[2][64*64];
  __shared__ u16 Vs[2][64*64];

  // hoist Q fragments (B-operand): q row = a-lane
  const u16* qptr = Qg + ((size_t)bh*NS + q)*NDK;
  short8 qf[2];
#pragma unroll
  for (int dkh=0; dkh<2; ++dkh)
    qf[dkh] = mk8(*(const ushort4*)(qptr + 32*dkh + 4*g),
                  *(const ushort4*)(qptr + 32*dkh + 16 + 4*g));

  float mrun = -1e30f, ls = 0.f;
  f32x4 accO[4] = {};

  // staging geometry: 256 threads x 2 x 16B per tile
  const int srow = tid >> 3;          // 0..31
  const int scol = (tid & 7) * 8;     // u16 col
  const size_t kbase = (size_t)bh * NS;
  const size_t vbase = (size_t)bh * NDK;

  // prologue: stage tile 0 into buffer 0
#pragma unroll
  for (int i=0;i<2;++i){
    const int r = srow + i*32;
    *(uint4*)&Ks[0][SW(r, scol)] = *(const uint4*)(Kg  + (kbase + r)*NDK + scol);
    *(uint4*)&Vs[0][SW(r, scol)] = *(const uint4*)(Vtg + (vbase + r)*NS + scol);
  }
  __syncthreads();

  int cur = 0;
#pragma unroll 1
  for (int t=0; t<nt; ++t){
    const int kv0 = t * 64;
    const bool have_next = (t+1 < nt);
    uint4 knx[2], vnx[2];
    if (have_next){                      // T14: issue global loads early
      const int kv1 = kv0 + 64;
#pragma unroll
      for (int i=0;i<2;++i){
        const int r = srow + i*32;
        knx[i] = *(const uint4*)(Kg  + (kbase + kv1 + r)*NDK + scol);
        vnx[i] = *(const uint4*)(Vtg + (vbase + r)*NS + kv1 + scol);
      }
    }

    const u16* Kb = Ks[cur];
    const u16* Vb = Vs[cur];
    // S^T = K * Q^T : lane holds S^T[kv0+kvf*16+4g+r][q]
    f32x4 sc[4] = {};
    __builtin_amdgcn_s_setprio(1);
#pragma unroll
    for (int kvf=0; kvf<4; ++kvf){
      const int rr = kvf*16 + a;
      const int rsw = (rr&7)<<3;
      const u16* rp = Kb + rr*64;
      short8 kf0 = mk8(*(const ushort4*)(rp + ((4*g)^rsw)),
                       *(const ushort4*)(rp + ((16+4*g)^rsw)));
      short8 kf1 = mk8(*(const ushort4*)(rp + ((32+4*g)^rsw)),
                       *(const ushort4*)(rp + ((48+4*g)^rsw)));
      sc[kvf] = __builtin_amdgcn_mfma_f32_16x16x32_bf16(kf0, qf[0], sc[kvf], 0,0,0);
      sc[kvf] = __builtin_amdgcn_mfma_f32_16x16x32_bf16(kf1, qf[1], sc[kvf], 0,0,0);
    }
    __builtin_amdgcn_s_setprio(0);

    // causal mask only on the diagonal tile (t == qb)
    float tmax = -1e30f;
    if (t == qb){
#pragma unroll
      for (int kvf=0;kvf<4;++kvf)
#pragma unroll
        for (int r=0;r<4;++r){
          const int kv = kv0 + kvf*16 + 4*g + r;
          if (kv > q) sc[kvf][r] = -1e30f;
          tmax = fmaxf(tmax, sc[kvf][r]);
        }
    } else {
#pragma unroll
      for (int kvf=0;kvf<4;++kvf)
#pragma unroll
        for (int r=0;r<4;++r) tmax = fmaxf(tmax, sc[kvf][r]);
    }
    tmax = fmaxf(tmax, __shfl_xor(tmax,16));
    tmax = fmaxf(tmax, __shfl_xor(tmax,32));

    // defer-max (T13): skip rescale while tile max stays within 8 (exp2 domain)
    if (!__all(tmax <= mrun + 8.0f)){
      const float mnew = fmaxf(mrun, tmax);
      const float fsc = exp2f(mrun - mnew);
      ls *= fsc;
#pragma unroll
      for (int dkg=0;dkg<4;++dkg) accO[dkg] *= fsc;
      mrun = mnew;
    }
    float rsum = 0.f;
    short8 pf0, pf1;
#pragma unroll
    for (int kvf=0;kvf<4;++kvf)
#pragma unroll
      for (int r=0;r<4;++r){
        const float p = exp2f(sc[kvf][r] - mrun);
        rsum += p;
        if (kvf<2) pf0[(kvf&1)*4+r] = (short)f2bf(p);
        else       pf1[(kvf&1)*4+r] = (short)f2bf(p);
      }
    rsum += __shfl_xor(rsum,16);
    rsum += __shfl_xor(rsum,32);
    ls += rsum;

    // PV: out^T(dk x q) += V^T * P^T (P in-register as B-operand)
    __builtin_amdgcn_s_setprio(1);
#pragma unroll
    for (int dkg=0;dkg<4;++dkg){
      const int rr = dkg*16 + a;
      const int rsw = (rr&7)<<3;
      const u16* rp = Vb + rr*64;
      short8 vf0 = mk8(*(const ushort4*)(rp + ((4*g)^rsw)),
                       *(const ushort4*)(rp + ((16+4*g)^rsw)));
      short8 vf1 = mk8(*(const ushort4*)(rp + ((32+4*g)^rsw)),
                       *(const ushort4*)(rp + ((48+4*g)^rsw)));
      accO[dkg] = __builtin_amdgcn_mfma_f32_16x16x32_bf16(vf0, pf0, accO[dkg], 0,0,0);
      accO[dkg] = __builtin_amdgcn_mfma_f32_16x16x32_bf16(vf1, pf1, accO[dkg], 0,0,0);
    }
    __builtin_amdgcn_s_setprio(0);

    if (have_next){                      // T14: LDS write after compute
#pragma unroll
      for (int i=0;i<2;++i){
        const int r = srow + i*32;
        *(uint4*)&Ks[cur^1][SW(r, scol)] = knx[i];
        *(uint4*)&Vs[cur^1][SW(r, scol)] = vnx[i];
      }
    }
    __syncthreads();
    cur ^= 1;
  }

  // epilogue: lane's acc belongs to q; dk = dkg*16 + 4g + r
  const float inv = 1.0f / ls;
  const int b = bh >> 4, h = bh & 15;
  u16* op = Og + ((size_t)b*NS + q)*ND + h*NDK;
#pragma unroll
  for (int dkg=0; dkg<4; ++dkg){
    ushort4 st;
    st.x = f2bf(accO[dkg][0]*inv);
    st.y = f2bf(accO[dkg][1]*inv);
    st.z = f2bf(accO[dkg][2]*inv);
    st.w = f2bf(accO[dkg][3]*inv);
    *(ushort4*)(op + dkg*16 + 4*g) = st;
  }
}

extern "C" void kernel_launch(void* const* d_in, const int* in_sizes, int n_in,
                              void* d_out, int out_size, void* d_ws, size_t ws_size,
                              hipStream_t stream) {
  (void)in_sizes; (void)n_in; (void)out_size; (void)ws_size;
  const float* x  = (const float*)d_in[0];
  // d_in[1] = mask: causal triu(k=1), hardcoded in attn kernel
  const float* Wq = (const float*)d_in[2];
  const float* bq = (const float*)d_in[3];
  const float* Wk = (const float*)d_in[4];
  const float* bk = (const float*)d_in[5];
  const float* Wv = (const float*)d_in[6];
  const float* bv = (const float*)d_in[7];
  const float* Wo = (const float*)d_in[8];
  const float* bo = (const float*)d_in[9];
  float* out = (float*)d_out;

  // ws layout (u16 elems, 40MB): Wt[4M] | Q[4M] | K[4M] | Vt[4M] | XO[4M]
  // XO is time-shared: holds bf16(x) for the QKV GEMM, then O from attention
  // (QKV GEMM finishes before attn writes O; attn never reads XO).
  u16* Wt  = (u16*)d_ws;
  u16* Qb  = Wt  + (size_t)4194304;
  u16* Kb  = Qb  + (size_t)4194304;
  u16* Vtb = Kb  + (size_t)4194304;
  u16* XO  = Vtb + (size_t)4194304;

  transpose_w_kernel<<<dim3(32,32,4), dim3(32,8,1), 0, stream>>>(Wq, Wk, Wv, Wo, Wt);
  cast_x_kernel<<<dim3(2048), dim3(256), 0, stream>>>(x, XO);
  gemm_kernel<0><<<dim3(8,32,3), dim3(256), 0, stream>>>(
      XO, Wt, bq, bk, bv, Qb, Kb, Vtb, (float*)nullptr);
  attn_kernel<<<dim3(32,32), dim3(256), 0, stream>>>(Qb, Kb, Vtb, XO);
  gemm_kernel<1><<<dim3(8,32,1), dim3(256), 0, stream>>>(
      XO, Wt + (size_t)3*1048576, bo, nullptr, nullptr,
      (u16*)nullptr, (u16*)nullptr, (u16*)nullptr, out);
}